// Round 3
// baseline (133.764 us; speedup 1.0000x reference)
//
#include <hip/hip_runtime.h>
#include <math.h>

#define NB 2
#define NN 768
#define ND 64

// barrier'd f32 ops: block FMA contraction / reassociation so rounding
// matches the numpy f32 reference bit-for-bit on sensitive chains
__device__ __forceinline__ float fmul_(float a, float b) { float r = a * b; asm volatile("" : "+v"(r)); return r; }
__device__ __forceinline__ float fadd_(float a, float b) { float r = a + b; asm volatile("" : "+v"(r)); return r; }

// numpy pairwise_sum for n=64: 8 accumulators striding 8, then
// ((r0+r1)+(r2+r3)) + ((r4+r5)+(r6+r7))
template <typename F>
__device__ __forceinline__ float pw64(F f) {
  float r[8];
#pragma unroll
  for (int m = 0; m < 8; ++m) r[m] = f(m);
#pragma unroll
  for (int i = 1; i < 8; ++i) {
#pragma unroll
    for (int m = 0; m < 8; ++m) r[m] = fadd_(r[m], f(8 * i + m));
  }
  const float s01 = fadd_(r[0], r[1]), s23 = fadd_(r[2], r[3]);
  const float s45 = fadd_(r[4], r[5]), s67 = fadd_(r[6], r[7]);
  return fadd_(fadd_(s01, s23), fadd_(s45, s67));
}

// correctly-rounded n/d given r = fl(1/d) (Markstein refinement; operands in
// benign exponent range here: d in [6e-5,4], n in [0,4])
__device__ __forceinline__ float div_rn(float n, float d, float r) {
  const float q0 = n * r;
  const float e  = __builtin_fmaf(-d, q0, n);
  return __builtin_fmaf(e, r, q0);
}

// K1: transpose X -> XT[b][k][i] + per-row n_i with numpy-pairwise rounding
__global__ __launch_bounds__(64) void k_setup(const float* __restrict__ x,
                                              float* __restrict__ XT,
                                              float* __restrict__ nrm) {
  const int row = blockIdx.x;            // b*NN + i
  const int b = row / NN, i = row - b * NN;
  const int k = threadIdx.x;
  __shared__ float sx[ND];
  const float xv = x[row * ND + k];
  XT[(b * ND + k) * NN + i] = xv;
  sx[k] = fmul_(xv, xv);
  __syncthreads();
  if (k == 0) nrm[row] = pw64([&](int kk) { return sx[kk]; });
}

// K2: one row i per block; Phase A computes per-pair coeffs faithfully (f32,
// numpy op order); Phase B accumulates support; epilogue expmap+mobius+proj.
__global__ __launch_bounds__(256) void k_main(const float* __restrict__ x,
                                              const float* __restrict__ adj,
                                              const float* __restrict__ attW,
                                              const float* __restrict__ attb,
                                              const float* __restrict__ XT,
                                              const float* __restrict__ nrm,
                                              float* __restrict__ out) {
  __shared__ float xi_s[ND];
  __shared__ float sW2[ND];
  __shared__ float cfs[NN];
  __shared__ float qp[4][ND];
  __shared__ float sP[4];
  __shared__ float eb[3][ND];

  const int row = blockIdx.x;            // 0..1535 = b*NN + i
  const int b = row / NN;
  const int tid = threadIdx.x;
  const int wv = tid >> 6, lane = tid & 63;

  if (tid < ND) xi_s[tid] = x[(size_t)row * ND + tid];
  else if (tid < 2 * ND) sW2[tid - ND] = attW[ND + (tid - ND)];
  __syncthreads();

  const float ni  = nrm[row];
  const float b1  = 1.0f - ni;                       // Sterbenz: exact
  const float lam = 2.0f / fmaxf(b1, 1e-15f);        // ref rounding
  const float g1  = 2.0f / lam;                      // double-rounded "2/lam"
  const float ab  = attb[0];
  const float ATH_CLIP = (float)(1.0 - 1e-07);

  const float* __restrict__ XTb  = XT + b * ND * NN;
  const float* __restrict__ nrmb = nrm + b * NN;

  float pP = 0.0f;
  for (int q = 0; q < 3; ++q) {
    const int j = q * 256 + tid;
    float rj[64];
#pragma unroll
    for (int k = 0; k < ND; ++k) rj[k] = XTb[k * NN + j];   // coalesced
    const float aj = adj[(size_t)row * NN + j];
    // d = numpy-pairwise sum of fl(xi_k * xj_k); xy = -d (exact negation)
    const float d  = pw64([&](int k) { return fmul_(xi_s[k], rj[k]); });
    const float xy = -d;
    const float nj = nrmb[j];
    const float t1  = fadd_(1.0f, 2.0f * xy);        // 2*xy exact
    const float a1  = fadd_(t1, nj);                 // 1 + 2c*xy + c*y2
    const float den = fadd_(t1, fmul_(ni, nj));      // 1 + 2c*xy + c^2*x2*y2
    const float denc = fmaxf(den, 1e-15f);
    const float rden = 1.0f / denc;                  // fl(1/denc)
    // pass 2: sub_k = fl(num_k/denc); s2 = pairwise(sub_k^2); subW = sub.W2
    float racc[8];
    float subW = 0.0f;
#pragma unroll
    for (int m = 0; m < 8; ++m) {
      const float nk = fadd_(-fmul_(a1, xi_s[m]), fmul_(b1, rj[m]));
      const float sk = div_rn(nk, denc, rden);
      subW = __builtin_fmaf(sk, sW2[m], subW);
      racc[m] = fmul_(sk, sk);
    }
#pragma unroll
    for (int i8 = 1; i8 < 8; ++i8) {
#pragma unroll
      for (int m = 0; m < 8; ++m) {
        const int k = 8 * i8 + m;
        const float nk = fadd_(-fmul_(a1, xi_s[k]), fmul_(b1, rj[k]));
        const float sk = div_rn(nk, denc, rden);
        subW = __builtin_fmaf(sk, sW2[k], subW);
        racc[m] = fadd_(racc[m], fmul_(sk, sk));
      }
    }
    const float s01 = fadd_(racc[0], racc[1]), s23 = fadd_(racc[2], racc[3]);
    const float s45 = fadd_(racc[4], racc[5]), s67 = fadd_(racc[6], racc[7]);
    const float s2  = fadd_(fadd_(s01, s23), fadd_(s45, s67));
    const float t   = sqrtf(s2);
    const float sn  = fmaxf(t, 1e-15f);              // sub_norm
    const float z   = fminf(sn, ATH_CLIP);
    const float ath = atanhf(z);
    const float g2  = fmul_(g1, ath);                // fl((2/lam)*artanh)
    const float gg  = g2 / sn;
    const float logit = gg * subW + ab;              // insensitive path
    const float sig   = 1.0f / (1.0f + expf(-logit));
    const float att   = sig * aj;                    // adj is exactly 0/1
    const float cfac  = att * gg * rden;             // folded scale (insens.)
    cfs[j] = cfac;
    pP = __builtin_fmaf(cfac, a1, pP);               // P = sum coeff*A
  }
  // block-reduce P
  float pw = pP;
#pragma unroll
  for (int m = 32; m >= 1; m >>= 1) pw += __shfl_xor(pw, m, 64);
  if (lane == 0) sP[wv] = pw;
  __syncthreads();

  // Phase B: Q[d] = sum_j cfac_j * x_j[d], j split across 4 waves
  float Qd = 0.0f;
  {
    const float* __restrict__ xb = x + (size_t)b * NN * ND;
    const int j0 = wv * (NN / 4);
    for (int jj = 0; jj < NN / 4; ++jj) {
      const int j = j0 + jj;
      Qd = __builtin_fmaf(cfs[j], xb[(size_t)j * ND + lane], Qd);
    }
  }
  qp[wv][lane] = Qd;
  __syncthreads();

  if (wv == 0) {
    const float P = (sP[0] + sP[1]) + (sP[2] + sP[3]);
    const float Q = (qp[0][lane] + qp[1][lane]) + (qp[2][lane] + qp[3][lane]);
    const float xid = xi_s[lane];
    float u = b1 * Q - P * xid;                      // support_t (insens. fold)
    u = fminf(fmaxf(u, -1e6f), 1e6f);                // clip
    // ---- expmap (faithful f32) ----
    eb[0][lane] = fmul_(u, u);
    const float u2 = pw64([&](int k) { return eb[0][k]; });
    const float un = fmaxf(sqrtf(u2), 1e-15f);
    const float th = tanhf(fmul_(0.5f * lam, un));   // 0.5*lam exact
    const float sec = fmul_(th, u) / un;             // second_d
    eb[0][lane] = fmul_(sec, sec);
    eb[1][lane] = fmul_(xid, sec);
    const float y2  = pw64([&](int k) { return eb[0][k]; });
    const float xys = pw64([&](int k) { return eb[1][k]; });
    // ---- mobius_add(p, second) ----
    const float t1e  = fadd_(1.0f, 2.0f * xys);
    const float a1e  = fadd_(t1e, y2);
    const float dene = fmaxf(fadd_(t1e, fmul_(ni, y2)), 1e-15f);
    const float o    = fadd_(fmul_(a1e, xid), fmul_(b1, sec)) / dene;
    // ---- proj ----
    eb[2][lane] = fmul_(o, o);
    const float o2 = pw64([&](int k) { return eb[2][k]; });
    const float nm = fmaxf(sqrtf(o2), 1e-15f);
    const float res = (nm > 0.996f) ? fmul_(o / nm, 0.996f) : o;
    out[(size_t)row * ND + lane] = res;
  }
}

extern "C" void kernel_launch(void* const* d_in, const int* in_sizes, int n_in,
                              void* d_out, int out_size, void* d_ws, size_t ws_size,
                              hipStream_t stream) {
  const float* x    = (const float*)d_in[0];
  const float* adj  = (const float*)d_in[1];
  const float* attW = (const float*)d_in[2];
  const float* attb = (const float*)d_in[3];
  float* out = (float*)d_out;

  char*  ws  = (char*)d_ws;
  float* XT  = (float*)ws;                                    // NB*ND*NN f32
  float* nrm = (float*)(ws + (size_t)NB * ND * NN * sizeof(float)); // NB*NN f32

  hipLaunchKernelGGL(k_setup, dim3(NB * NN), dim3(ND), 0, stream, x, XT, nrm);
  hipLaunchKernelGGL(k_main, dim3(NB * NN), dim3(256), 0, stream,
                     x, adj, attW, attb, XT, nrm, out);
}

// Round 4
// 90.661 us; speedup vs baseline: 1.4754x; 1.4754x over previous
//
#include <hip/hip_runtime.h>
#include <math.h>

#define NB 2
#define NN 768
#define ND 64

// barrier'd f32 ops: block FMA contraction / reassociation so rounding
// matches the numpy f32 reference bit-for-bit on sensitive chains
__device__ __forceinline__ float fmul_(float a, float b) { float r = a * b; asm volatile("" : "+v"(r)); return r; }
__device__ __forceinline__ float fadd_(float a, float b) { float r = a + b; asm volatile("" : "+v"(r)); return r; }

// numpy pairwise_sum for n=64: 8 accumulators striding 8, then
// ((r0+r1)+(r2+r3)) + ((r4+r5)+(r6+r7))
template <typename F>
__device__ __forceinline__ float pw64(F f) {
  float r[8];
#pragma unroll
  for (int m = 0; m < 8; ++m) r[m] = f(m);
#pragma unroll
  for (int i = 1; i < 8; ++i) {
#pragma unroll
    for (int m = 0; m < 8; ++m) r[m] = fadd_(r[m], f(8 * i + m));
  }
  const float s01 = fadd_(r[0], r[1]), s23 = fadd_(r[2], r[3]);
  const float s45 = fadd_(r[4], r[5]), s67 = fadd_(r[6], r[7]);
  return fadd_(fadd_(s01, s23), fadd_(s45, s67));
}

// correctly-rounded n/d given r = fl(1/d) (Markstein refinement; benign range)
__device__ __forceinline__ float div_rn(float n, float d, float r) {
  const float q0 = n * r;
  const float e  = __builtin_fmaf(-d, q0, n);
  return __builtin_fmaf(e, r, q0);
}

// One wave per row. Ballot-compact nonzero adj cols (~5% density), run the
// bit-faithful per-pair chain only on those, then Q/P accumulate + epilogue.
__global__ __launch_bounds__(64) void k_main(const float* __restrict__ x,
                                             const float* __restrict__ adj,
                                             const float* __restrict__ attW,
                                             const float* __restrict__ attb,
                                             float* __restrict__ out) {
  __shared__ float xi_s[ND];
  __shared__ float sW2[ND];
  __shared__ float eb[ND];
  __shared__ int   lj[NN];
  __shared__ float lcf[NN];

  const int row  = blockIdx.x;           // 0..1535 = b*NN + i
  const int b    = row / NN;
  const int lane = threadIdx.x;          // 0..63

  xi_s[lane] = x[(size_t)row * ND + lane];
  sW2[lane]  = attW[ND + lane];
  __syncthreads();

  // n_i with numpy-pairwise rounding (bitwise same as old k_setup path)
  eb[lane] = fmul_(xi_s[lane], xi_s[lane]);
  __syncthreads();
  const float ni = pw64([&](int k) { return eb[k]; });

  const float b1  = 1.0f - ni;                       // Sterbenz: exact
  const float lam = 2.0f / fmaxf(b1, 1e-15f);        // ref rounding
  const float g1  = 2.0f / lam;                      // double-rounded "2/lam"
  const float ab  = attb[0];
  const float ATH_CLIP = (float)(1.0 - 1e-07);

  // ---- compact nonzero adj columns, ascending j ----
  int count = 0;
  const float* __restrict__ arow = adj + (size_t)row * NN;
#pragma unroll
  for (int c = 0; c < NN / 64; ++c) {
    const int j = c * 64 + lane;
    const float aj = arow[j];
    const unsigned long long m = __ballot(aj != 0.0f);
    if (aj != 0.0f) {
      const int rank = __popcll(m & ((1ull << lane) - 1ull));
      lj[count + rank] = j;
    }
    count += __popcll(m);                // wave-uniform
  }
  __syncthreads();

  // ---- Phase A: per-pair chain (bitwise identical to dense version) ----
  const float* __restrict__ xb = x + (size_t)b * NN * ND;
  float pP = 0.0f;
  for (int p = lane; p < count; p += 64) {
    const int j = lj[p];
    float rj[ND];
    const float4* __restrict__ xj4 = (const float4*)(xb + (size_t)j * ND);
#pragma unroll
    for (int k4 = 0; k4 < 16; ++k4) {
      const float4 v = xj4[k4];
      rj[4 * k4 + 0] = v.x; rj[4 * k4 + 1] = v.y;
      rj[4 * k4 + 2] = v.z; rj[4 * k4 + 3] = v.w;
    }
    // n_j recomputed with the same fmul_/pw64 sequence -> bitwise identical
    const float nj = pw64([&](int k) { return fmul_(rj[k], rj[k]); });
    const float d  = pw64([&](int k) { return fmul_(xi_s[k], rj[k]); });
    const float xy = -d;
    const float t1  = fadd_(1.0f, 2.0f * xy);        // 2*xy exact
    const float a1  = fadd_(t1, nj);                 // 1 + 2c*xy + c*y2
    const float den = fadd_(t1, fmul_(ni, nj));      // 1 + 2c*xy + c^2*x2*y2
    const float denc = fmaxf(den, 1e-15f);
    const float rden = 1.0f / denc;
    float racc[8];
    float subW = 0.0f;
#pragma unroll
    for (int m = 0; m < 8; ++m) {
      const float nk = fadd_(-fmul_(a1, xi_s[m]), fmul_(b1, rj[m]));
      const float sk = div_rn(nk, denc, rden);
      subW = __builtin_fmaf(sk, sW2[m], subW);
      racc[m] = fmul_(sk, sk);
    }
#pragma unroll
    for (int i8 = 1; i8 < 8; ++i8) {
#pragma unroll
      for (int m = 0; m < 8; ++m) {
        const int k = 8 * i8 + m;
        const float nk = fadd_(-fmul_(a1, xi_s[k]), fmul_(b1, rj[k]));
        const float sk = div_rn(nk, denc, rden);
        subW = __builtin_fmaf(sk, sW2[k], subW);
        racc[m] = fadd_(racc[m], fmul_(sk, sk));
      }
    }
    const float s01 = fadd_(racc[0], racc[1]), s23 = fadd_(racc[2], racc[3]);
    const float s45 = fadd_(racc[4], racc[5]), s67 = fadd_(racc[6], racc[7]);
    const float s2  = fadd_(fadd_(s01, s23), fadd_(s45, s67));
    const float t   = sqrtf(s2);
    const float sn  = fmaxf(t, 1e-15f);              // sub_norm
    const float z   = fminf(sn, ATH_CLIP);
    const float ath = atanhf(z);
    const float g2  = fmul_(g1, ath);                // fl((2/lam)*artanh)
    const float gg  = g2 / sn;
    const float logit = gg * subW + ab;
    const float sig   = 1.0f / (1.0f + expf(-logit));
    const float cfac  = sig * gg * rden;             // att = sig*1.0 exactly
    lcf[p] = cfac;
    pP = __builtin_fmaf(cfac, a1, pP);               // P = sum coeff*A
  }
  // wave-reduce P (scalar; reorder noise ~1e-7, not amplified)
  float pw = pP;
#pragma unroll
  for (int m = 32; m >= 1; m >>= 1) pw += __shfl_xor(pw, m, 64);
  const float P = pw;
  __syncthreads();

  // ---- Phase B: Q[d], keeping the old 4-quarter-chain tree bitwise ----
  float Q0 = 0.0f, Q1 = 0.0f, Q2 = 0.0f, Q3 = 0.0f;
  for (int p = 0; p < count; ++p) {
    const int j  = lj[p];                // wave-uniform (LDS broadcast)
    const float cf = lcf[p];
    const float v  = xb[(size_t)j * ND + lane];   // coalesced row read
    if (j < 192)      Q0 = __builtin_fmaf(cf, v, Q0);
    else if (j < 384) Q1 = __builtin_fmaf(cf, v, Q1);
    else if (j < 576) Q2 = __builtin_fmaf(cf, v, Q2);
    else              Q3 = __builtin_fmaf(cf, v, Q3);
  }
  const float Q = (Q0 + Q1) + (Q2 + Q3);

  // ---- epilogue: expmap + mobius + proj (verbatim from passing version) ----
  const float xid = xi_s[lane];
  float u = b1 * Q - P * xid;                        // support_t
  u = fminf(fmaxf(u, -1e6f), 1e6f);                  // clip
  __syncthreads();
  eb[lane] = fmul_(u, u);
  __syncthreads();
  const float u2 = pw64([&](int k) { return eb[k]; });
  const float un = fmaxf(sqrtf(u2), 1e-15f);
  const float th = tanhf(fmul_(0.5f * lam, un));     // 0.5*lam exact
  const float sec = fmul_(th, u) / un;               // second_d
  __syncthreads();
  eb[lane] = fmul_(sec, sec);
  __syncthreads();
  const float y2 = pw64([&](int k) { return eb[k]; });
  __syncthreads();
  eb[lane] = fmul_(xid, sec);
  __syncthreads();
  const float xys = pw64([&](int k) { return eb[k]; });
  const float t1e  = fadd_(1.0f, 2.0f * xys);
  const float a1e  = fadd_(t1e, y2);
  const float dene = fmaxf(fadd_(t1e, fmul_(ni, y2)), 1e-15f);
  const float o    = fadd_(fmul_(a1e, xid), fmul_(b1, sec)) / dene;
  __syncthreads();
  eb[lane] = fmul_(o, o);
  __syncthreads();
  const float o2 = pw64([&](int k) { return eb[k]; });
  const float nm = fmaxf(sqrtf(o2), 1e-15f);
  const float res = (nm > 0.996f) ? fmul_(o / nm, 0.996f) : o;
  out[(size_t)row * ND + lane] = res;
}

extern "C" void kernel_launch(void* const* d_in, const int* in_sizes, int n_in,
                              void* d_out, int out_size, void* d_ws, size_t ws_size,
                              hipStream_t stream) {
  const float* x    = (const float*)d_in[0];
  const float* adj  = (const float*)d_in[1];
  const float* attW = (const float*)d_in[2];
  const float* attb = (const float*)d_in[3];
  float* out = (float*)d_out;

  hipLaunchKernelGGL(k_main, dim3(NB * NN), dim3(64), 0, stream,
                     x, adj, attW, attb, out);
}

// Round 5
// 85.083 us; speedup vs baseline: 1.5722x; 1.0655x over previous
//
#include <hip/hip_runtime.h>
#include <math.h>

#define NB 2
#define NN 768
#define ND 64
#define XSTRIDE 68   // floats; 272 B rows: 16B-aligned for b128, read conflict-free

// barrier'd f32 ops: block FMA contraction / reassociation so rounding
// matches the numpy f32 reference bit-for-bit on sensitive chains
__device__ __forceinline__ float fmul_(float a, float b) { float r = a * b; asm volatile("" : "+v"(r)); return r; }
__device__ __forceinline__ float fadd_(float a, float b) { float r = a + b; asm volatile("" : "+v"(r)); return r; }

// numpy pairwise_sum for n=64: 8 accumulators striding 8, then
// ((r0+r1)+(r2+r3)) + ((r4+r5)+(r6+r7))
template <typename F>
__device__ __forceinline__ float pw64(F f) {
  float r[8];
#pragma unroll
  for (int m = 0; m < 8; ++m) r[m] = f(m);
#pragma unroll
  for (int i = 1; i < 8; ++i) {
#pragma unroll
    for (int m = 0; m < 8; ++m) r[m] = fadd_(r[m], f(8 * i + m));
  }
  const float s01 = fadd_(r[0], r[1]), s23 = fadd_(r[2], r[3]);
  const float s45 = fadd_(r[4], r[5]), s67 = fadd_(r[6], r[7]);
  return fadd_(fadd_(s01, s23), fadd_(s45, s67));
}

// correctly-rounded n/d given r = fl(1/d) (Markstein refinement; benign range)
__device__ __forceinline__ float div_rn(float n, float d, float r) {
  const float q0 = n * r;
  const float e  = __builtin_fmaf(-d, q0, n);
  return __builtin_fmaf(e, r, q0);
}

// One wave per row. Ballot-compact nonzero adj cols (~5% density), run the
// bit-faithful per-pair chain on those; Phase B runs from LDS-staged rows
// (no data-dependent global loads). Output bitwise-identical to round-4.
__global__ __launch_bounds__(64) void k_main(const float* __restrict__ x,
                                             const float* __restrict__ adj,
                                             const float* __restrict__ attW,
                                             const float* __restrict__ attb,
                                             float* __restrict__ out) {
  __shared__ float xi_s[ND];
  __shared__ float sW2[ND];
  __shared__ float eb[ND];
  __shared__ short lj[NN];
  __shared__ float lcf_s[64];
  __shared__ float lds_x[64 * XSTRIDE];

  const int row  = blockIdx.x;           // 0..1535 = b*NN + i
  const int b    = row / NN;
  const int lane = threadIdx.x;          // 0..63

  xi_s[lane] = x[(size_t)row * ND + lane];
  sW2[lane]  = attW[ND + lane];

  // hoist adjacency chunk loads (overlap with n_i computation below)
  const float* __restrict__ arow = adj + (size_t)row * NN;
  float av[NN / 64];
#pragma unroll
  for (int c = 0; c < NN / 64; ++c) av[c] = arow[c * 64 + lane];

  __syncthreads();

  // n_i with numpy-pairwise rounding (bitwise same as round-4)
  eb[lane] = fmul_(xi_s[lane], xi_s[lane]);
  __syncthreads();
  const float ni = pw64([&](int k) { return eb[k]; });

  const float b1  = 1.0f - ni;                       // Sterbenz: exact
  const float lam = 2.0f / fmaxf(b1, 1e-15f);        // ref rounding
  const float g1  = 2.0f / lam;                      // double-rounded "2/lam"
  const float ab  = attb[0];
  const float ATH_CLIP = (float)(1.0 - 1e-07);

  // ---- compact nonzero adj columns, ascending j (same scan as round-4) ----
  int count = 0;
#pragma unroll
  for (int c = 0; c < NN / 64; ++c) {
    const unsigned long long m = __ballot(av[c] != 0.0f);
    if (av[c] != 0.0f) {
      const int rank = __popcll(m & ((1ull << lane) - 1ull));
      lj[count + rank] = (short)(c * 64 + lane);
    }
    count += __popcll(m);                // wave-uniform
  }
  __syncthreads();

  const float* __restrict__ xb = x + (size_t)b * NN * ND;
  float pP = 0.0f;
  float Q0 = 0.0f, Q1 = 0.0f, Q2 = 0.0f, Q3 = 0.0f;

  for (int base = 0; base < count; base += 64) {
    const int valid = min(count - base, 64);

    // ---- Phase A: per-pair chain (bitwise identical to round-4) ----
    if (lane < valid) {
      const int j = lj[base + lane];
      float rj[ND];
      const float4* __restrict__ xj4 = (const float4*)(xb + (size_t)j * ND);
#pragma unroll
      for (int k4 = 0; k4 < 16; ++k4) {
        const float4 v = xj4[k4];
        rj[4 * k4 + 0] = v.x; rj[4 * k4 + 1] = v.y;
        rj[4 * k4 + 2] = v.z; rj[4 * k4 + 3] = v.w;
      }
      // stage row into LDS for Phase B (values, not rounding, so layout free)
      {
        float4* __restrict__ dst = (float4*)&lds_x[lane * XSTRIDE];
#pragma unroll
        for (int k4 = 0; k4 < 16; ++k4)
          dst[k4] = make_float4(rj[4 * k4], rj[4 * k4 + 1],
                                rj[4 * k4 + 2], rj[4 * k4 + 3]);
      }
      const float nj = pw64([&](int k) { return fmul_(rj[k], rj[k]); });
      const float d  = pw64([&](int k) { return fmul_(xi_s[k], rj[k]); });
      const float xy = -d;
      const float t1  = fadd_(1.0f, 2.0f * xy);      // 2*xy exact
      const float a1  = fadd_(t1, nj);               // 1 + 2c*xy + c*y2
      const float den = fadd_(t1, fmul_(ni, nj));    // 1 + 2c*xy + c^2*x2*y2
      const float denc = fmaxf(den, 1e-15f);
      const float rden = 1.0f / denc;
      float racc[8];
      float subW = 0.0f;
#pragma unroll
      for (int m = 0; m < 8; ++m) {
        const float nk = fadd_(-fmul_(a1, xi_s[m]), fmul_(b1, rj[m]));
        const float sk = div_rn(nk, denc, rden);
        subW = __builtin_fmaf(sk, sW2[m], subW);
        racc[m] = fmul_(sk, sk);
      }
#pragma unroll
      for (int i8 = 1; i8 < 8; ++i8) {
#pragma unroll
        for (int m = 0; m < 8; ++m) {
          const int k = 8 * i8 + m;
          const float nk = fadd_(-fmul_(a1, xi_s[k]), fmul_(b1, rj[k]));
          const float sk = div_rn(nk, denc, rden);
          subW = __builtin_fmaf(sk, sW2[k], subW);
          racc[m] = fadd_(racc[m], fmul_(sk, sk));
        }
      }
      const float s01 = fadd_(racc[0], racc[1]), s23 = fadd_(racc[2], racc[3]);
      const float s45 = fadd_(racc[4], racc[5]), s67 = fadd_(racc[6], racc[7]);
      const float s2  = fadd_(fadd_(s01, s23), fadd_(s45, s67));
      const float t   = sqrtf(s2);
      const float sn  = fmaxf(t, 1e-15f);            // sub_norm
      const float z   = fminf(sn, ATH_CLIP);
      const float ath = atanhf(z);
      const float g2  = fmul_(g1, ath);              // fl((2/lam)*artanh)
      const float gg  = g2 / sn;
      const float logit = gg * subW + ab;
      const float sig   = 1.0f / (1.0f + expf(-logit));
      const float cfac  = sig * gg * rden;           // att = sig*1.0 exactly
      lcf_s[lane] = cfac;
      pP = __builtin_fmaf(cfac, a1, pP);             // P = sum coeff*A
    }
    __syncthreads();

    // ---- Phase B: Q quarter-chains from LDS, ascending p (round-4 tree) ----
    for (int p2 = 0; p2 < valid; ++p2) {
      const int   j  = lj[base + p2];                // wave-uniform broadcast
      const float cf = lcf_s[p2];
      const float v  = lds_x[p2 * XSTRIDE + lane];   // conflict-free
      if (j < 192)      Q0 = __builtin_fmaf(cf, v, Q0);
      else if (j < 384) Q1 = __builtin_fmaf(cf, v, Q1);
      else if (j < 576) Q2 = __builtin_fmaf(cf, v, Q2);
      else              Q3 = __builtin_fmaf(cf, v, Q3);
    }
    __syncthreads();                                 // before re-staging
  }

  // wave-reduce P (scalar; reorder noise ~1e-7, not amplified)
  float pw = pP;
#pragma unroll
  for (int m = 32; m >= 1; m >>= 1) pw += __shfl_xor(pw, m, 64);
  const float P = pw;
  const float Q = (Q0 + Q1) + (Q2 + Q3);

  // ---- epilogue: expmap + mobius + proj (verbatim from round-4) ----
  const float xid = xi_s[lane];
  float u = b1 * Q - P * xid;                        // support_t
  u = fminf(fmaxf(u, -1e6f), 1e6f);                  // clip
  __syncthreads();
  eb[lane] = fmul_(u, u);
  __syncthreads();
  const float u2 = pw64([&](int k) { return eb[k]; });
  const float un = fmaxf(sqrtf(u2), 1e-15f);
  const float th = tanhf(fmul_(0.5f * lam, un));     // 0.5*lam exact
  const float sec = fmul_(th, u) / un;               // second_d
  __syncthreads();
  eb[lane] = fmul_(sec, sec);
  __syncthreads();
  const float y2 = pw64([&](int k) { return eb[k]; });
  __syncthreads();
  eb[lane] = fmul_(xid, sec);
  __syncthreads();
  const float xys = pw64([&](int k) { return eb[k]; });
  const float t1e  = fadd_(1.0f, 2.0f * xys);
  const float a1e  = fadd_(t1e, y2);
  const float dene = fmaxf(fadd_(t1e, fmul_(ni, y2)), 1e-15f);
  const float o    = fadd_(fmul_(a1e, xid), fmul_(b1, sec)) / dene;
  __syncthreads();
  eb[lane] = fmul_(o, o);
  __syncthreads();
  const float o2 = pw64([&](int k) { return eb[k]; });
  const float nm = fmaxf(sqrtf(o2), 1e-15f);
  const float res = (nm > 0.996f) ? fmul_(o / nm, 0.996f) : o;
  out[(size_t)row * ND + lane] = res;
}

extern "C" void kernel_launch(void* const* d_in, const int* in_sizes, int n_in,
                              void* d_out, int out_size, void* d_ws, size_t ws_size,
                              hipStream_t stream) {
  const float* x    = (const float*)d_in[0];
  const float* adj  = (const float*)d_in[1];
  const float* attW = (const float*)d_in[2];
  const float* attb = (const float*)d_in[3];
  float* out = (float*)d_out;

  hipLaunchKernelGGL(k_main, dim3(NB * NN), dim3(64), 0, stream,
                     x, adj, attW, attb, out);
}

// Round 6
// 79.126 us; speedup vs baseline: 1.6905x; 1.0753x over previous
//
#include <hip/hip_runtime.h>
#include <math.h>

#define NB 2
#define NN 768
#define ND 64
#define XSTRIDE 68   // floats; 272 B rows: 16B-aligned writes, conflict-free reads

// barrier'd f32 ops: block FMA contraction / reassociation so rounding
// matches the numpy f32 reference bit-for-bit on sensitive chains
__device__ __forceinline__ float fmul_(float a, float b) { float r = a * b; asm volatile("" : "+v"(r)); return r; }
__device__ __forceinline__ float fadd_(float a, float b) { float r = a + b; asm volatile("" : "+v"(r)); return r; }

// numpy pairwise_sum for n=64 over a per-lane register array:
// 8 accumulators striding 8, then ((r0+r1)+(r2+r3)) + ((r4+r5)+(r6+r7))
template <typename F>
__device__ __forceinline__ float pw64(F f) {
  float r[8];
#pragma unroll
  for (int m = 0; m < 8; ++m) r[m] = f(m);
#pragma unroll
  for (int i = 1; i < 8; ++i) {
#pragma unroll
    for (int m = 0; m < 8; ++m) r[m] = fadd_(r[m], f(8 * i + m));
  }
  const float s01 = fadd_(r[0], r[1]), s23 = fadd_(r[2], r[3]);
  const float s45 = fadd_(r[4], r[5]), s67 = fadd_(r[6], r[7]);
  return fadd_(fadd_(s01, s23), fadd_(s45, s67));
}

// shuffle-based pairwise sum over lane-distributed values (lane k holds f(k)).
// Bitwise-identical to pw64: stage 1 accumulates v[m],v[m+8],... sequentially
// (same order); butterfly combine matches the balanced tree up to fp-add
// COMMUTATIVITY (a+b == b+a bitwise in IEEE RN), which preserves rounding.
__device__ __forceinline__ float pwShfl(float v, int lane) {
  const int m = lane & 7;
  float s = __shfl(v, m);
#pragma unroll
  for (int i = 1; i < 8; ++i) s = fadd_(s, __shfl(v, m + 8 * i));
  s = fadd_(s, __shfl_xor(s, 1));
  s = fadd_(s, __shfl_xor(s, 2));
  s = fadd_(s, __shfl_xor(s, 4));
  return s;
}

// correctly-rounded n/d given r = fl(1/d) (Markstein refinement; benign range)
__device__ __forceinline__ float div_rn(float n, float d, float r) {
  const float q0 = n * r;
  const float e  = __builtin_fmaf(-d, q0, n);
  return __builtin_fmaf(e, r, q0);
}

// One wave per row. Ballot-compact nonzero adj cols (~5% density), run the
// bit-faithful per-pair chain on those; Phase B from LDS-staged rows with
// register-shuffle coefficient broadcast; all reductions via shuffles.
// Output bitwise-identical to rounds 4/5.
__global__ __launch_bounds__(64) void k_main(const float* __restrict__ x,
                                             const float* __restrict__ adj,
                                             const float* __restrict__ attW,
                                             const float* __restrict__ attb,
                                             float* __restrict__ out) {
  __shared__ float xi_s[ND];
  __shared__ float sW2[ND];
  __shared__ short lj[NN];
  __shared__ float lds_x[64 * XSTRIDE];

  const int row  = blockIdx.x;           // 0..1535 = b*NN + i
  const int b    = row / NN;
  const int lane = threadIdx.x;          // 0..63

  const float xiv = x[(size_t)row * ND + lane];
  xi_s[lane] = xiv;
  sW2[lane]  = attW[ND + lane];

  // hoist adjacency chunk loads (independent; overlap with n_i computation)
  const float* __restrict__ arow = adj + (size_t)row * NN;
  float av[NN / 64];
#pragma unroll
  for (int c = 0; c < NN / 64; ++c) av[c] = arow[c * 64 + lane];

  // n_i with numpy-pairwise rounding (bitwise same as rounds 3-5)
  const float ni = pwShfl(fmul_(xiv, xiv), lane);

  const float b1  = 1.0f - ni;                       // Sterbenz: exact
  const float lam = 2.0f / fmaxf(b1, 1e-15f);        // ref rounding
  const float g1  = 2.0f / lam;                      // double-rounded "2/lam"
  const float ab  = attb[0];
  const float ATH_CLIP = (float)(1.0 - 1e-07);

  // ---- compact nonzero adj columns, ascending j ----
  int count = 0;
#pragma unroll
  for (int c = 0; c < NN / 64; ++c) {
    const unsigned long long m = __ballot(av[c] != 0.0f);
    if (av[c] != 0.0f) {
      const int rank = __popcll(m & ((1ull << lane) - 1ull));
      lj[count + rank] = (short)(c * 64 + lane);
    }
    count += __popcll(m);                // wave-uniform
  }
  __syncthreads();

  const float* __restrict__ xb = x + (size_t)b * NN * ND;
  float pP = 0.0f;
  float Q0 = 0.0f, Q1 = 0.0f, Q2 = 0.0f, Q3 = 0.0f;
  float cfv = 0.0f;                      // per-lane pair coeff (shfl source)
  int   jv  = NN;                        // per-lane pair col   (shfl source)

  for (int base = 0; base < count; base += 64) {
    const int valid = min(count - base, 64);

    // ---- Phase A: per-pair chain (bitwise identical to rounds 4/5) ----
    if (lane < valid) {
      const int j = lj[base + lane];
      jv = j;
      float rj[ND];
      const float4* __restrict__ xj4 = (const float4*)(xb + (size_t)j * ND);
#pragma unroll
      for (int k4 = 0; k4 < 16; ++k4) {
        const float4 v = xj4[k4];
        rj[4 * k4 + 0] = v.x; rj[4 * k4 + 1] = v.y;
        rj[4 * k4 + 2] = v.z; rj[4 * k4 + 3] = v.w;
      }
      // stage row into LDS for Phase B (values only; layout free)
      {
        float4* __restrict__ dst = (float4*)&lds_x[lane * XSTRIDE];
#pragma unroll
        for (int k4 = 0; k4 < 16; ++k4)
          dst[k4] = make_float4(rj[4 * k4], rj[4 * k4 + 1],
                                rj[4 * k4 + 2], rj[4 * k4 + 3]);
      }
      const float nj = pw64([&](int k) { return fmul_(rj[k], rj[k]); });
      const float d  = pw64([&](int k) { return fmul_(xi_s[k], rj[k]); });
      const float xy = -d;
      const float t1  = fadd_(1.0f, 2.0f * xy);      // 2*xy exact
      const float a1  = fadd_(t1, nj);               // 1 + 2c*xy + c*y2
      const float den = fadd_(t1, fmul_(ni, nj));    // 1 + 2c*xy + c^2*x2*y2
      const float denc = fmaxf(den, 1e-15f);
      const float rden = 1.0f / denc;
      float racc[8];
      float subW = 0.0f;
#pragma unroll
      for (int m = 0; m < 8; ++m) {
        const float nk = fadd_(-fmul_(a1, xi_s[m]), fmul_(b1, rj[m]));
        const float sk = div_rn(nk, denc, rden);
        subW = __builtin_fmaf(sk, sW2[m], subW);
        racc[m] = fmul_(sk, sk);
      }
#pragma unroll
      for (int i8 = 1; i8 < 8; ++i8) {
#pragma unroll
        for (int m = 0; m < 8; ++m) {
          const int k = 8 * i8 + m;
          const float nk = fadd_(-fmul_(a1, xi_s[k]), fmul_(b1, rj[k]));
          const float sk = div_rn(nk, denc, rden);
          subW = __builtin_fmaf(sk, sW2[k], subW);
          racc[m] = fadd_(racc[m], fmul_(sk, sk));
        }
      }
      const float s01 = fadd_(racc[0], racc[1]), s23 = fadd_(racc[2], racc[3]);
      const float s45 = fadd_(racc[4], racc[5]), s67 = fadd_(racc[6], racc[7]);
      const float s2  = fadd_(fadd_(s01, s23), fadd_(s45, s67));
      const float t   = sqrtf(s2);
      const float sn  = fmaxf(t, 1e-15f);            // sub_norm
      const float z   = fminf(sn, ATH_CLIP);
      const float ath = atanhf(z);
      const float g2  = fmul_(g1, ath);              // fl((2/lam)*artanh)
      const float gg  = g2 / sn;
      const float logit = gg * subW + ab;
      const float sig   = 1.0f / (1.0f + expf(-logit));
      const float cfac  = sig * gg * rden;           // att = sig*1.0 exactly
      cfv = cfac;
      pP = __builtin_fmaf(cfac, a1, pP);             // P = sum coeff*A
    }
    __syncthreads();

    // ---- Phase B: Q quarter-chains, coeff/col via register shuffle ----
    for (int p2 = 0; p2 < valid; ++p2) {
      const float cf = __shfl(cfv, p2);
      const int   jb = __shfl(jv, p2);
      const float v  = lds_x[p2 * XSTRIDE + lane];   // conflict-free
      if (jb < 192)      Q0 = __builtin_fmaf(cf, v, Q0);
      else if (jb < 384) Q1 = __builtin_fmaf(cf, v, Q1);
      else if (jb < 576) Q2 = __builtin_fmaf(cf, v, Q2);
      else               Q3 = __builtin_fmaf(cf, v, Q3);
    }
    __syncthreads();                                 // before re-staging
  }

  // wave-reduce P (scalar; reorder noise ~1e-7, not amplified)
  float pw = pP;
#pragma unroll
  for (int m = 32; m >= 1; m >>= 1) pw += __shfl_xor(pw, m, 64);
  const float P = pw;
  const float Q = (Q0 + Q1) + (Q2 + Q3);

  // ---- epilogue: expmap + mobius + proj (same ops; shuffle reductions) ----
  float u = b1 * Q - P * xiv;                        // support_t
  u = fminf(fmaxf(u, -1e6f), 1e6f);                  // clip
  const float u2 = pwShfl(fmul_(u, u), lane);
  const float un = fmaxf(sqrtf(u2), 1e-15f);
  const float th = tanhf(fmul_(0.5f * lam, un));     // 0.5*lam exact
  const float sec = fmul_(th, u) / un;               // second_d
  const float y2  = pwShfl(fmul_(sec, sec), lane);
  const float xys = pwShfl(fmul_(xiv, sec), lane);
  const float t1e  = fadd_(1.0f, 2.0f * xys);
  const float a1e  = fadd_(t1e, y2);
  const float dene = fmaxf(fadd_(t1e, fmul_(ni, y2)), 1e-15f);
  const float o    = fadd_(fmul_(a1e, xiv), fmul_(b1, sec)) / dene;
  const float o2 = pwShfl(fmul_(o, o), lane);
  const float nm = fmaxf(sqrtf(o2), 1e-15f);
  const float res = (nm > 0.996f) ? fmul_(o / nm, 0.996f) : o;
  out[(size_t)row * ND + lane] = res;
}

extern "C" void kernel_launch(void* const* d_in, const int* in_sizes, int n_in,
                              void* d_out, int out_size, void* d_ws, size_t ws_size,
                              hipStream_t stream) {
  const float* x    = (const float*)d_in[0];
  const float* adj  = (const float*)d_in[1];
  const float* attW = (const float*)d_in[2];
  const float* attb = (const float*)d_in[3];
  float* out = (float*)d_out;

  hipLaunchKernelGGL(k_main, dim3(NB * NN), dim3(64), 0, stream,
                     x, adj, attW, attb, out);
}

// Round 7
// 74.515 us; speedup vs baseline: 1.7951x; 1.0619x over previous
//
#include <hip/hip_runtime.h>
#include <math.h>

#define NB 2
#define NN 768
#define ND 64
#define XSTRIDE 68   // floats; 272 B rows: 16B-aligned writes, conflict-free reads

// barrier'd f32 ops: block FMA contraction / reassociation so rounding
// matches the numpy f32 reference bit-for-bit on sensitive chains
__device__ __forceinline__ float fmul_(float a, float b) { float r = a * b; asm volatile("" : "+v"(r)); return r; }
__device__ __forceinline__ float fadd_(float a, float b) { float r = a + b; asm volatile("" : "+v"(r)); return r; }

// numpy pairwise_sum for n=64 over a per-lane register array:
// 8 accumulators striding 8, then ((r0+r1)+(r2+r3)) + ((r4+r5)+(r6+r7))
template <typename F>
__device__ __forceinline__ float pw64(F f) {
  float r[8];
#pragma unroll
  for (int m = 0; m < 8; ++m) r[m] = f(m);
#pragma unroll
  for (int i = 1; i < 8; ++i) {
#pragma unroll
    for (int m = 0; m < 8; ++m) r[m] = fadd_(r[m], f(8 * i + m));
  }
  const float s01 = fadd_(r[0], r[1]), s23 = fadd_(r[2], r[3]);
  const float s45 = fadd_(r[4], r[5]), s67 = fadd_(r[6], r[7]);
  return fadd_(fadd_(s01, s23), fadd_(s45, s67));
}

// shuffle-based pairwise sum over lane-distributed values (lane k holds v_k).
// Bitwise-identical to pw64 (stage-1 same order; butterfly = balanced tree up
// to fp-add commutativity, which preserves rounding).
__device__ __forceinline__ float pwShfl(float v, int lane) {
  const int m = lane & 7;
  float s = __shfl(v, m);
#pragma unroll
  for (int i = 1; i < 8; ++i) s = fadd_(s, __shfl(v, m + 8 * i));
  s = fadd_(s, __shfl_xor(s, 1));
  s = fadd_(s, __shfl_xor(s, 2));
  s = fadd_(s, __shfl_xor(s, 4));
  return s;
}

// two independent pairwise sums, interleaved so the serial shuffle chains
// overlap; each result bitwise-identical to pwShfl of that input alone
__device__ __forceinline__ void pwShfl2(float va, float vb, int lane,
                                        float& sa, float& sb) {
  const int m = lane & 7;
  float a = __shfl(va, m), b = __shfl(vb, m);
#pragma unroll
  for (int i = 1; i < 8; ++i) {
    a = fadd_(a, __shfl(va, m + 8 * i));
    b = fadd_(b, __shfl(vb, m + 8 * i));
  }
  a = fadd_(a, __shfl_xor(a, 1)); b = fadd_(b, __shfl_xor(b, 1));
  a = fadd_(a, __shfl_xor(a, 2)); b = fadd_(b, __shfl_xor(b, 2));
  a = fadd_(a, __shfl_xor(a, 4)); b = fadd_(b, __shfl_xor(b, 4));
  sa = a; sb = b;
}

// correctly-rounded n/d given r = fl(1/d) (Markstein refinement; benign range)
__device__ __forceinline__ float div_rn(float n, float d, float r) {
  const float q0 = n * r;
  const float e  = __builtin_fmaf(-d, q0, n);
  return __builtin_fmaf(e, r, q0);
}

// One wave per row. Ballot-compact nonzero adj cols (~5% density) with
// quarter boundaries recorded (lj ascending => quarters are contiguous p
// ranges); bit-faithful per-pair chain; Phase B = four tight per-quarter
// loops (1 shfl + 1 ds_read + 1 fma per pair). Output bitwise = rounds 4-6.
__global__ __launch_bounds__(64) void k_main(const float* __restrict__ x,
                                             const float* __restrict__ adj,
                                             const float* __restrict__ attW,
                                             const float* __restrict__ attb,
                                             float* __restrict__ out) {
  __shared__ float xi_s[ND];
  __shared__ float sW2[ND];
  __shared__ short lj[NN];
  __shared__ float lds_x[64 * XSTRIDE];

  const int row  = blockIdx.x;           // 0..1535 = b*NN + i
  const int b    = row / NN;
  const int lane = threadIdx.x;          // 0..63

  const float xiv = x[(size_t)row * ND + lane];
  xi_s[lane] = xiv;
  sW2[lane]  = attW[ND + lane];

  // hoist adjacency chunk loads (independent; overlap with n_i computation)
  const float* __restrict__ arow = adj + (size_t)row * NN;
  float av[NN / 64];
#pragma unroll
  for (int c = 0; c < NN / 64; ++c) av[c] = arow[c * 64 + lane];

  // n_i with numpy-pairwise rounding (bitwise same as rounds 3-6)
  const float ni = pwShfl(fmul_(xiv, xiv), lane);

  const float b1  = 1.0f - ni;                       // Sterbenz: exact
  const float lam = 2.0f / fmaxf(b1, 1e-15f);        // ref rounding
  const float g1  = 2.0f / lam;                      // double-rounded "2/lam"
  const float ab  = attb[0];
  const float ATH_CLIP = (float)(1.0 - 1e-07);

  // ---- compact nonzero adj columns, ascending j; record quarter bounds ----
  int count = 0, qb1 = 0, qb2 = 0, qb3 = 0;
#pragma unroll
  for (int c = 0; c < NN / 64; ++c) {
    const unsigned long long m = __ballot(av[c] != 0.0f);
    if (av[c] != 0.0f) {
      const int rank = __popcll(m & ((1ull << lane) - 1ull));
      lj[count + rank] = (short)(c * 64 + lane);
    }
    count += __popcll(m);                // wave-uniform
    if (c == 2) qb1 = count;             // end of j<192
    if (c == 5) qb2 = count;             // end of j<384
    if (c == 8) qb3 = count;             // end of j<576
  }
  __syncthreads();

  const float* __restrict__ xb = x + (size_t)b * NN * ND;
  float pP = 0.0f;
  float Q0 = 0.0f, Q1 = 0.0f, Q2 = 0.0f, Q3 = 0.0f;
  float cfv = 0.0f;                      // per-lane pair coeff (shfl source)

  for (int base = 0; base < count; base += 64) {
    const int valid = min(count - base, 64);

    // ---- Phase A: per-pair chain (bitwise identical to rounds 4-6) ----
    if (lane < valid) {
      const int j = lj[base + lane];
      float rj[ND];
      const float4* __restrict__ xj4 = (const float4*)(xb + (size_t)j * ND);
#pragma unroll
      for (int k4 = 0; k4 < 16; ++k4) {
        const float4 v = xj4[k4];
        rj[4 * k4 + 0] = v.x; rj[4 * k4 + 1] = v.y;
        rj[4 * k4 + 2] = v.z; rj[4 * k4 + 3] = v.w;
      }
      // stage row into LDS for Phase B (values only; layout free)
      {
        float4* __restrict__ dst = (float4*)&lds_x[lane * XSTRIDE];
#pragma unroll
        for (int k4 = 0; k4 < 16; ++k4)
          dst[k4] = make_float4(rj[4 * k4], rj[4 * k4 + 1],
                                rj[4 * k4 + 2], rj[4 * k4 + 3]);
      }
      const float nj = pw64([&](int k) { return fmul_(rj[k], rj[k]); });
      const float d  = pw64([&](int k) { return fmul_(xi_s[k], rj[k]); });
      const float xy = -d;
      const float t1  = fadd_(1.0f, 2.0f * xy);      // 2*xy exact
      const float a1  = fadd_(t1, nj);               // 1 + 2c*xy + c*y2
      const float den = fadd_(t1, fmul_(ni, nj));    // 1 + 2c*xy + c^2*x2*y2
      const float denc = fmaxf(den, 1e-15f);
      const float rden = 1.0f / denc;
      float racc[8];
      float subW = 0.0f;
#pragma unroll
      for (int m = 0; m < 8; ++m) {
        const float nk = fadd_(-fmul_(a1, xi_s[m]), fmul_(b1, rj[m]));
        const float sk = div_rn(nk, denc, rden);
        subW = __builtin_fmaf(sk, sW2[m], subW);
        racc[m] = fmul_(sk, sk);
      }
#pragma unroll
      for (int i8 = 1; i8 < 8; ++i8) {
#pragma unroll
        for (int m = 0; m < 8; ++m) {
          const int k = 8 * i8 + m;
          const float nk = fadd_(-fmul_(a1, xi_s[k]), fmul_(b1, rj[k]));
          const float sk = div_rn(nk, denc, rden);
          subW = __builtin_fmaf(sk, sW2[k], subW);
          racc[m] = fadd_(racc[m], fmul_(sk, sk));
        }
      }
      const float s01 = fadd_(racc[0], racc[1]), s23 = fadd_(racc[2], racc[3]);
      const float s45 = fadd_(racc[4], racc[5]), s67 = fadd_(racc[6], racc[7]);
      const float s2  = fadd_(fadd_(s01, s23), fadd_(s45, s67));
      const float t   = sqrtf(s2);
      const float sn  = fmaxf(t, 1e-15f);            // sub_norm
      const float z   = fminf(sn, ATH_CLIP);
      const float ath = atanhf(z);
      const float g2  = fmul_(g1, ath);              // fl((2/lam)*artanh)
      const float gg  = g2 / sn;
      const float logit = gg * subW + ab;
      const float sig   = 1.0f / (1.0f + expf(-logit));
      const float cfac  = sig * gg * rden;           // att = sig*1.0 exactly
      cfv = cfac;
      pP = __builtin_fmaf(cfac, a1, pP);             // P = sum coeff*A
    }
    __syncthreads();

    // ---- Phase B: four tight per-quarter loops (quarters contiguous in p;
    //      accumulation order within each Qq = ascending p, bitwise as before)
    const int lim = base + valid;
    {
      const int lo = max(0,   base), hi = min(qb1, lim);
      for (int p2 = lo; p2 < hi; ++p2)
        Q0 = __builtin_fmaf(__shfl(cfv, p2 - base),
                            lds_x[(p2 - base) * XSTRIDE + lane], Q0);
    }
    {
      const int lo = max(qb1, base), hi = min(qb2, lim);
      for (int p2 = lo; p2 < hi; ++p2)
        Q1 = __builtin_fmaf(__shfl(cfv, p2 - base),
                            lds_x[(p2 - base) * XSTRIDE + lane], Q1);
    }
    {
      const int lo = max(qb2, base), hi = min(qb3, lim);
      for (int p2 = lo; p2 < hi; ++p2)
        Q2 = __builtin_fmaf(__shfl(cfv, p2 - base),
                            lds_x[(p2 - base) * XSTRIDE + lane], Q2);
    }
    {
      const int lo = max(qb3, base), hi = min(count, lim);
      for (int p2 = lo; p2 < hi; ++p2)
        Q3 = __builtin_fmaf(__shfl(cfv, p2 - base),
                            lds_x[(p2 - base) * XSTRIDE + lane], Q3);
    }
    __syncthreads();                                 // before re-staging
  }

  // wave-reduce P (scalar; reorder noise ~1e-7, not amplified)
  float pw = pP;
#pragma unroll
  for (int m = 32; m >= 1; m >>= 1) pw += __shfl_xor(pw, m, 64);
  const float P = pw;
  const float Q = (Q0 + Q1) + (Q2 + Q3);

  // ---- epilogue: expmap + mobius + proj (same ops; shuffle reductions) ----
  float u = b1 * Q - P * xiv;                        // support_t
  u = fminf(fmaxf(u, -1e6f), 1e6f);                  // clip
  const float u2 = pwShfl(fmul_(u, u), lane);
  const float un = fmaxf(sqrtf(u2), 1e-15f);
  const float th = tanhf(fmul_(0.5f * lam, un));     // 0.5*lam exact
  const float sec = fmul_(th, u) / un;               // second_d
  float y2, xys;
  pwShfl2(fmul_(sec, sec), fmul_(xiv, sec), lane, y2, xys);
  const float t1e  = fadd_(1.0f, 2.0f * xys);
  const float a1e  = fadd_(t1e, y2);
  const float dene = fmaxf(fadd_(t1e, fmul_(ni, y2)), 1e-15f);
  const float o    = fadd_(fmul_(a1e, xiv), fmul_(b1, sec)) / dene;
  const float o2 = pwShfl(fmul_(o, o), lane);
  const float nm = fmaxf(sqrtf(o2), 1e-15f);
  const float res = (nm > 0.996f) ? fmul_(o / nm, 0.996f) : o;
  out[(size_t)row * ND + lane] = res;
}

extern "C" void kernel_launch(void* const* d_in, const int* in_sizes, int n_in,
                              void* d_out, int out_size, void* d_ws, size_t ws_size,
                              hipStream_t stream) {
  const float* x    = (const float*)d_in[0];
  const float* adj  = (const float*)d_in[1];
  const float* attW = (const float*)d_in[2];
  const float* attb = (const float*)d_in[3];
  float* out = (float*)d_out;

  hipLaunchKernelGGL(k_main, dim3(NB * NN), dim3(64), 0, stream,
                     x, adj, attW, attb, out);
}